// Round 17
// baseline (101.065 us; speedup 1.0000x reference)
//
#include <hip/hip_runtime.h>
#include <hip/hip_bf16.h>

typedef __attribute__((ext_vector_type(8))) short short8;
typedef __attribute__((ext_vector_type(4))) float f32x4;

// dims: S=128, E=256 -> 32768 pairs; H=20, D=64, A=64, NH=8
constexpr float TEMP = 2.5f;    // H / sqrt(A) = 20/8
constexpr float NEGV = -1e9f;

// ---- workspace layout (dwords) ----
constexpr int K_OFF  = 0;       // k[8][64] f32 (TEMP-scaled)
constexpr int P_OFF  = 512;     // p[8][64] f32 (TEMP-scaled; source for PFRAG)
constexpr int Q_OFF  = 1024;    // q[8]     f32 (TEMP-scaled)
constexpr int PFRAG  = 1040;    // P  B-frags [2 ks][2 s][64 lane][4 dw] (1024)
constexpr int MFRAG  = 2064;    // M  B-frags [8 n][2 ks][4 dt][2 s][64][4] (32768)
constexpr int WFRAG  = 34832;   // Wf B-frags SINGLE-plane [8 n][2 ks][4 dt][64][4] (16384)

// ---- main-kernel LDS layout ----
// u16 units:
constexpr int HS2_U   = 0;      // hs bf16 2-plane [2 s][8 p][20 m][72]
constexpr int HS2_PL  = 11520;  //   plane stride; pair 1440; row 72
                                //   (23040 u16; after barrier 2: y f32 @0)
constexpr int V2_U    = 23040;  // V bf16 2-plane [2 s][8 p][n*72+d]
constexpr int V2_PL   = 4672;   //   plane stride; pair 584 (8*72+8 pad)
                                //   (after P2: wv SINGLE-plane overlay in plane-0)
constexpr int HT2_U   = 32384;  // ht bf16 2-way [2 s][8 p][80] (1280 u16)
// f32/u32 units (u16 total 33664 -> f32 offset 16832):
constexpr int ATTP_F = 16832;   // attn packed bf16x2 [8 p][16 mp][9] u32 (1152)
constexpr int C_F    = 17984;   // c[8 p][8 n]               (64)
constexpr int LEN_F  = 18048;   // len[8]                    (8)
constexpr int LDS_FL = 18056;   // 72,224 B -> 2 blocks/CU

#define MFMA_B16 __builtin_amdgcn_mfma_f32_16x16x32_bf16

// ---- bf16 helpers ----
__device__ inline ushort bf16_rne(float x) {
  uint u = __float_as_uint(x);
  u += 0x7FFF + ((u >> 16) & 1);
  return (ushort)(u >> 16);
}
__device__ inline float bf16_f(ushort h) { return __uint_as_float(((uint)h) << 16); }
__device__ inline void split2(float x, ushort& h0, ushort& h1) {
  h0 = bf16_rne(x);
  h1 = bf16_rne(x - bf16_f(h0));
}
__device__ inline ushort split_lvl2(float x, int s) {
  ushort h0 = bf16_rne(x);
  return s == 0 ? h0 : bf16_rne(x - bf16_f(h0));
}
__device__ inline uint pkbf16x2(float a, float b) {
  __hip_bfloat162 h = __float22bfloat162_rn(make_float2(a, b));
  uint u; __builtin_memcpy(&u, &h, 4);
  return u;
}
__device__ inline uint2 pkbf16x4(float4 v) {
  uint2 r; r.x = pkbf16x2(v.x, v.y); r.y = pkbf16x2(v.z, v.w);
  return r;
}
// 4-float 2-plane split: u0 = bf16 pair-packed, u1 = packed residuals
__device__ inline void pksplit4(float4 v, uint2& u0, uint2& u1) {
  u0 = pkbf16x4(v);
  float4 r;
  r.x = v.x - __uint_as_float(u0.x << 16);
  r.y = v.y - __uint_as_float(u0.x & 0xffff0000u);
  r.z = v.z - __uint_as_float(u0.y << 16);
  r.w = v.w - __uint_as_float(u0.y & 0xffff0000u);
  u1 = pkbf16x4(r);
}
__device__ inline short8 pack4(uint a, uint b, uint c, uint d) {
  union { uint u[4]; short8 s; } cv;
  cv.u[0] = a; cv.u[1] = b; cv.u[2] = c; cv.u[3] = d;
  return cv.s;
}

// ============================================================
// prep (grid 17): 0..7 -> M[n] frags + k,p,q ; 8..15 -> Wf frags
//                 (single-plane) ; 16 -> P frags.  (unchanged, verified)
// ============================================================
__global__ __launch_bounds__(256) void prep_kernel(
    const float* __restrict__ Wt, const float* __restrict__ bt,
    const float* __restrict__ Ws, const float* __restrict__ bs,
    const float* __restrict__ Wf, float* __restrict__ ws) {
  __shared__ float AL[64 * 65];
  __shared__ float BL[64 * 65];
  __shared__ float ML[64 * 65];
  const int t = threadIdx.x;
  uint* wsu = (uint*)ws;
  if (blockIdx.x < 8) {
    const int n = blockIdx.x;
#pragma unroll
    for (int i = 0; i < 16; ++i) {
      int idx = i * 256 + t;
      AL[(idx >> 6) * 65 + (idx & 63)] = Wt[n * 4096 + idx];
      BL[(idx >> 6) * 65 + (idx & 63)] = Ws[n * 4096 + idx];
    }
    __syncthreads();
#pragma unroll
    for (int i = 0; i < 16; ++i) {            // M[dp][d] = Wt[dp]·Ws[d] * TEMP
      int idx = i * 256 + t;
      int dp = idx >> 6, d = idx & 63;
      float acc = 0.f;
#pragma unroll 8
      for (int a = 0; a < 64; ++a) acc += AL[dp * 65 + a] * BL[d * 65 + a];
      ML[dp * 65 + d] = acc * TEMP;
    }
    if (t < 64) {
      float acc = 0.f;
#pragma unroll 8
      for (int a = 0; a < 64; ++a) acc += BL[t * 65 + a] * bt[n * 64 + a];
      ws[K_OFF + n * 64 + t] = acc * TEMP;
    } else if (t < 128) {
      int r = t - 64;
      float acc = 0.f;
#pragma unroll 8
      for (int a = 0; a < 64; ++a) acc += AL[r * 65 + a] * bs[n * 64 + a];
      ws[P_OFF + n * 64 + r] = acc * TEMP;
    } else if (t == 128) {
      float acc = 0.f;
      for (int a = 0; a < 64; ++a) acc += bt[n * 64 + a] * bs[n * 64 + a];
      ws[Q_OFF + n] = acc * TEMP;
    }
    __syncthreads();
#pragma unroll
    for (int i = 0; i < 16; ++i) {            // 4096 frag dwords (2-way split)
      int f = i * 256 + t;
      int r = f & 3, lane = (f >> 2) & 63, g = f >> 8;
      int s = g & 1, dt = (g >> 1) & 3, ks = g >> 3;
      int k = ks * 32 + ((lane >> 4) & 3) * 8 + r * 2;
      int d = dt * 16 + (lane & 15);
      uint lo = split_lvl2(ML[k * 65 + d], s);
      uint hi = split_lvl2(ML[(k + 1) * 65 + d], s);
      wsu[MFRAG + n * 4096 + (((ks * 4 + dt) * 2 + s) * 64 + lane) * 4 + r] =
          lo | (hi << 16);
    }
  } else if (blockIdx.x < 16) {
    const int n = blockIdx.x - 8;
#pragma unroll
    for (int i = 0; i < 16; ++i) {            // Wf rows n*64.. (k=dd, col=d)
      int idx = i * 256 + t;
      AL[(idx >> 6) * 65 + (idx & 63)] = Wf[(n * 64 + (idx >> 6)) * 64 + (idx & 63)];
    }
    __syncthreads();
#pragma unroll
    for (int i = 0; i < 8; ++i) {             // 2048 frag dwords (single plane)
      int f = i * 256 + t;
      int r = f & 3, lane = (f >> 2) & 63, g = f >> 8;   // g 0..7
      int dt = g & 3, ks = g >> 2;
      int k = ks * 32 + ((lane >> 4) & 3) * 8 + r * 2;
      int d = dt * 16 + (lane & 15);
      uint lo = bf16_rne(AL[k * 65 + d]);
      uint hi = bf16_rne(AL[(k + 1) * 65 + d]);
      wsu[WFRAG + n * 2048 + ((ks * 4 + dt) * 64 + lane) * 4 + r] =
          lo | (hi << 16);
    }
  } else {
#pragma unroll
    for (int i = 0; i < 2; ++i) {
      int idx = i * 256 + t;                  // 0..511
      int n = idx >> 6, dp = idx & 63;
      float acc = 0.f;
#pragma unroll 8
      for (int a = 0; a < 64; ++a)
        acc += Wt[n * 4096 + dp * 64 + a] * bs[n * 64 + a];
      AL[idx] = acc * TEMP;                   // pL[n][dp]
    }
    __syncthreads();
#pragma unroll
    for (int i = 0; i < 4; ++i) {
      int f = i * 256 + t;
      int r = f & 3, lane = (f >> 2) & 63, g = f >> 8;
      int s = g & 1, ks = g >> 1;
      int k = ks * 32 + ((lane >> 4) & 3) * 8 + r * 2;
      int col = lane & 15;
      uint lo = (col < 8) ? (uint)split_lvl2(AL[col * 64 + k], s) : 0u;
      uint hi = (col < 8) ? (uint)split_lvl2(AL[col * 64 + k + 1], s) : 0u;
      wsu[PFRAG + ((ks * 2 + s) * 64 + lane) * 4 + r] = lo | (hi << 16);
    }
  }
}

// 2-way split-product cluster for global frags (verified R7)
#define SPLIT2_MFMA(FB, DT, CC)                                      \
  {                                                                  \
    short8 b00 = *(const short8*)&(FB)[((0 * 4 + (DT)) * 2 + 0) * 256]; \
    short8 b01 = *(const short8*)&(FB)[((0 * 4 + (DT)) * 2 + 1) * 256]; \
    short8 b10 = *(const short8*)&(FB)[((1 * 4 + (DT)) * 2 + 0) * 256]; \
    short8 b11 = *(const short8*)&(FB)[((1 * 4 + (DT)) * 2 + 1) * 256]; \
    CC = MFMA_B16(a00, b00, CC, 0, 0, 0);                            \
    CC = MFMA_B16(a10, b10, CC, 0, 0, 0);                            \
    CC = MFMA_B16(a00, b01, CC, 0, 0, 0);                            \
    CC = MFMA_B16(a01, b00, CC, 0, 0, 0);                            \
    CC = MFMA_B16(a10, b11, CC, 0, 0, 0);                            \
    CC = MFMA_B16(a11, b10, CC, 0, 0, 0);                            \
  }

// A-frag loads: a00/a10 = plane0 (k-chunk 0/1), a01/a11 = plane1
#define LOAD_A(BASEU, ROWSTR, PLANESTR, ROW, KOFF)                   \
  short8 a00 = *(const short8*)&(BASEU)[(ROW) * (ROWSTR) + (KOFF)];               \
  short8 a01 = *(const short8*)&(BASEU)[(PLANESTR) + (ROW) * (ROWSTR) + (KOFF)];  \
  short8 a10 = *(const short8*)&(BASEU)[(ROW) * (ROWSTR) + 32 + (KOFF)];          \
  short8 a11 = *(const short8*)&(BASEU)[(PLANESTR) + (ROW) * (ROWSTR) + 32 + (KOFF)];

// hs reg-staging index math (quad f = I*512 + t)
#define HV_LOAD(I, DST)                                                      \
  {                                                                          \
    const int f_ = (I) * 512 + t;                                            \
    const int p_ = f_ / 320;                                                 \
    const int s_ = f_ - p_ * 320;                                            \
    DST = *(const float4*)(hs_g + (size_t)(pair0 + p_) * 1280 +              \
                           (s_ >> 4) * 64 + (s_ & 15) * 4);                  \
  }
#define HV_STORE(I, SRC)                                                     \
  {                                                                          \
    const int f_ = (I) * 512 + t;                                            \
    const int p_ = f_ / 320;                                                 \
    const int s_ = f_ - p_ * 320;                                            \
    uint2 u0_, u1_; pksplit4(SRC, u0_, u1_);                                 \
    ushort* d_ = ldsu + HS2_U + p_ * 1440 + (s_ >> 4) * 72 + (s_ & 15) * 4;  \
    *(uint2*)d_ = u0_;                                                       \
    *(uint2*)(d_ + HS2_PL) = u1_;                                            \
  }

// ============================================================
// main: 8 pairs/block, 512 threads (8 waves), grid 4096, 2 blocks/CU.
// R15 structure (ht via LDS broadcast, barrier A restored); hs global
// loads issued BEFORE the V phase so MFMA chain covers their latency.
// ============================================================
__global__ __launch_bounds__(512, 4) void attn_kernel(
    const float* __restrict__ ht_g, const float* __restrict__ hs_g,
    const int* __restrict__ len_g, const float* __restrict__ bf,
    const float* __restrict__ wsp, float* __restrict__ out) {
  __shared__ __align__(16) float lds[LDS_FL];
  ushort* ldsu = (ushort*)lds;
  const int t    = threadIdx.x;
  const int lane = t & 63;
  const int w    = t >> 6;
  const int pair0 = blockIdx.x * 8;
  const uint* wsu = (const uint*)wsp;
  const int lo4 = lane & 15, kg = lane >> 4;
  const int rp8 = lo4 & 7;
  const int dtw = w & 3, ngw = w >> 2;

  // ---------- prefetch Wf frags (single-plane) for P4a ----------
  short8 wfB0[4], wfB1[4];
#pragma unroll
  for (int nn = 0; nn < 4; ++nn) {
    const uint* fb = wsu + WFRAG + (ngw * 4 + nn) * 2048 + lane * 4;
    wfB0[nn] = *(const short8*)&fb[(0 * 4 + dtw) * 256];
    wfB1[nn] = *(const short8*)&fb[(1 * 4 + dtw) * 256];
  }

  // ---------- stage ht (2-way bf16 split) + len ----------
  {
    float x = ht_g[(size_t)pair0 * 64 + t];
    ushort h0, h1; split2(x, h0, h1);
    const int p = t >> 6, dp = t & 63;
    ldsu[HT2_U + 0 * 640 + p * 80 + dp] = h0;
    ldsu[HT2_U + 1 * 640 + p * 80 + dp] = h1;
  }
  if (t < 8) lds[LEN_F + t] = (float)len_g[pair0 + t];
  __syncthreads();   // barrier A: ht2 visible

  // ---------- issue hs global loads EARLY (V-phase MFMAs cover them) -----
  float4 hv0, hv1, hv2, hv3, hv4;
  HV_LOAD(0, hv0) HV_LOAD(1, hv1) HV_LOAD(2, hv2) HV_LOAD(3, hv3) HV_LOAD(4, hv4)

  // ---------- V phase (MFMA): wave = head n; V -> 2-plane bf16 -----------
  {
    const int n = w;
    LOAD_A(ldsu + HT2_U, 80, 640, rp8, kg * 8)
    const uint* fb = wsu + MFRAG + n * 4096 + lane * 4;
    const float* kb = &wsp[K_OFF + n * 64 + lo4];
    float kv0 = kb[0], kv1 = kb[16], kv2 = kb[32], kv3 = kb[48];
    f32x4 c0 = {kv0, kv0, kv0, kv0};
    f32x4 c1 = {kv1, kv1, kv1, kv1};
    f32x4 c2 = {kv2, kv2, kv2, kv2};
    f32x4 c3 = {kv3, kv3, kv3, kv3};
    __builtin_amdgcn_s_setprio(1);
    SPLIT2_MFMA(fb, 0, c0)
    SPLIT2_MFMA(fb, 1, c1)
    SPLIT2_MFMA(fb, 2, c2)
    SPLIT2_MFMA(fb, 3, c3)
    __builtin_amdgcn_s_setprio(0);
    if (kg < 2) {
#pragma unroll
      for (int reg = 0; reg < 4; ++reg) {
        const int p = kg * 4 + reg;
        ushort* vp = ldsu + V2_U + p * 584 + n * 72 + lo4;
        ushort h0, h1;
        split2(c0[reg], h0, h1); vp[0]  = h0; vp[V2_PL]      = h1;
        split2(c1[reg], h0, h1); vp[16] = h0; vp[V2_PL + 16] = h1;
        split2(c2[reg], h0, h1); vp[32] = h0; vp[V2_PL + 32] = h1;
        split2(c3[reg], h0, h1); vp[48] = h0; vp[V2_PL + 48] = h1;
      }
    }
  }

  // ---------- c (MFMA, wave 0): c[p][n] = q[n] + ht_p·p_n ----------
  if (w == 0) {
    LOAD_A(ldsu + HT2_U, 80, 640, rp8, kg * 8)
    const uint* fbp = wsu + PFRAG + lane * 4;
    short8 b00 = *(const short8*)&fbp[0 * 256];
    short8 b01 = *(const short8*)&fbp[1 * 256];
    short8 b10 = *(const short8*)&fbp[2 * 256];
    short8 b11 = *(const short8*)&fbp[3 * 256];
    float qv = (lo4 < 8) ? wsp[Q_OFF + lo4] : 0.f;
    f32x4 cc = {qv, qv, qv, qv};
    cc = MFMA_B16(a00, b00, cc, 0, 0, 0);
    cc = MFMA_B16(a10, b10, cc, 0, 0, 0);
    cc = MFMA_B16(a00, b01, cc, 0, 0, 0);
    cc = MFMA_B16(a01, b00, cc, 0, 0, 0);
    cc = MFMA_B16(a10, b11, cc, 0, 0, 0);
    cc = MFMA_B16(a11, b10, cc, 0, 0, 0);
    if (kg < 2 && lo4 < 8) {
#pragma unroll
      for (int reg = 0; reg < 4; ++reg)
        lds[C_F + (kg * 4 + reg) * 8 + lo4] = cc[reg];
    }
  }

  // ---------- convert staged hs -> 2-plane bf16 LDS ----------
  HV_STORE(0, hv0) HV_STORE(1, hv1) HV_STORE(2, hv2) HV_STORE(3, hv3) HV_STORE(4, hv4)
  __syncthreads();   // barrier 1: V2, c, hs2 visible

  // ---------- P2 (MFMA): scores + softmax. wave = pair ----------
  {
    const int p = w;
    const int n8 = rp8;
    const int lenp = (int)lds[LEN_F + p];
    const ushort* vb = ldsu + V2_U + p * 584 + n8 * 72;
    const short8 B00 = *(const short8*)&vb[kg * 8];                // ks0 s0
    const short8 B01 = *(const short8*)&vb[V2_PL + kg * 8];        // ks0 s1
    const short8 B10 = *(const short8*)&vb[32 + kg * 8];           // ks1 s0
    const short8 B11 = *(const short8*)&vb[V2_PL + 32 + kg * 8];   // ks1 s1
    const float cv = lds[C_F + p * 8 + n8];
    f32x4 acc0 = {cv, cv, cv, cv};
    f32x4 acc1 = {cv, cv, cv, cv};
    __builtin_amdgcn_s_setprio(1);
    {
      const ushort* ab = ldsu + HS2_U + p * 1440;
      LOAD_A(ab, 72, HS2_PL, lo4, kg * 8)                          // rows 0..15
      acc0 = MFMA_B16(a00, B00, acc0, 0, 0, 0);
      acc0 = MFMA_B16(a10, B10, acc0, 0, 0, 0);
      acc0 = MFMA_B16(a00, B01, acc0, 0, 0, 0);
      acc0 = MFMA_B16(a01, B00, acc0, 0, 0, 0);
      acc0 = MFMA_B16(a10, B11, acc0, 0, 0, 0);
      acc0 = MFMA_B16(a11, B10, acc0, 0, 0, 0);
    }
    {
      const int row = (16 + lo4 < 20) ? (16 + lo4) : 19;           // clamp pad
      const ushort* ab = ldsu + HS2_U + p * 1440;
      LOAD_A(ab, 72, HS2_PL, row, kg * 8)
      acc1 = MFMA_B16(a00, B00, acc1, 0, 0, 0);
      acc1 = MFMA_B16(a10, B10, acc1, 0, 0, 0);
      acc1 = MFMA_B16(a00, B01, acc1, 0, 0, 0);
      acc1 = MFMA_B16(a01, B00, acc1, 0, 0, 0);
      acc1 = MFMA_B16(a10, B11, acc1, 0, 0, 0);
      acc1 = MFMA_B16(a11, B10, acc1, 0, 0, 0);
    }
    __builtin_amdgcn_s_setprio(0);
    // softmax over m (verified pattern)
    float e0[4], e1[4];
    float mx = NEGV;
#pragma unroll
    for (int r = 0; r < 4; ++r) {
      const int m0 = kg * 4 + r;
      const int m1 = 16 + kg * 4 + r;
      e0[r] = (m0 < lenp) ? acc0[r] : NEGV;
      e1[r] = (m1 < lenp) ? acc1[r] : NEGV;
      mx = fmaxf(mx, fmaxf(e0[r], e1[r]));
    }
    mx = fmaxf(mx, __shfl_xor(mx, 16));
    mx = fmaxf(mx, __shfl_xor(mx, 32));
    float sm = 0.f;
#pragma unroll
    for (int r = 0; r < 4; ++r) {
      e0[r] = __expf(e0[r] - mx);
      e1[r] = (kg == 0) ? __expf(e1[r] - mx) : 0.f;    // pad rows m>=20 -> 0
      sm += e0[r] + e1[r];
    }
    sm += __shfl_xor(sm, 16);
    sm += __shfl_xor(sm, 32);
    const float inv = 1.0f / sm;
    // ---- pack attn as bf16 pairs: attp[p][mp][n], mp = m/2, stride 9 ----
    uint* attp = (uint*)&lds[ATTP_F] + p * 144;
    if (lo4 < 8) {
      attp[(kg * 2 + 0) * 9 + lo4] = pkbf16x2(e0[0] * inv, e0[1] * inv);
      attp[(kg * 2 + 1) * 9 + lo4] = pkbf16x2(e0[2] * inv, e0[3] * inv);
      if (kg == 0) {
        attp[8 * 9 + lo4] = pkbf16x2(e1[0] * inv, e1[1] * inv);
        attp[9 * 9 + lo4] = pkbf16x2(e1[2] * inv, e1[3] * inv);
      } else if (kg == 1) {
        attp[14 * 9 + lo4] = 0u; attp[15 * 9 + lo4] = 0u;
      } else if (kg == 2) {
        attp[10 * 9 + lo4] = 0u; attp[11 * 9 + lo4] = 0u;
      } else {
        attp[12 * 9 + lo4] = 0u; attp[13 * 9 + lo4] = 0u;
      }
    }
  }
  // no barrier: P3 pair-local (same wave wrote this pair's attn)

  // ---------- P3 (MFMA): wv[n][d] = sum_m attn[m][n]*hs0[m][d] -----------
  // A: pre-packed bf16 attn pairs, row=n, k=m. B: hs plane-0 scattered.
  // wv output SINGLE-plane bf16 (verified R15).
  {
    const int p = w;
    const uint* attp = (const uint*)&lds[ATTP_F] + p * 144;
    const ushort* hsb = ldsu + HS2_U + p * 1440;
    uint a_[4];
#pragma unroll
    for (int r = 0; r < 4; ++r)
      a_[r] = attp[(kg * 4 + r) * 9 + rp8];    // broadcast across lo4>=8
    const short8 A = pack4(a_[0], a_[1], a_[2], a_[3]);
    ushort* wp = ldsu + V2_U + p * 584;        // overlay V2 plane-0 (dead)
#pragma unroll
    for (int dt = 0; dt < 4; ++dt) {
      uint b_[4];
#pragma unroll
      for (int r = 0; r < 4; ++r) {
        const int m0 = kg * 8 + 2 * r;
        const int d = dt * 16 + lo4;
        uint blo = (m0 < 20) ? (uint)hsb[m0 * 72 + d] : 0u;
        uint bhi = (m0 + 1 < 20) ? (uint)hsb[(m0 + 1) * 72 + d] : 0u;
        b_[r] = blo | (bhi << 16);
      }
      const short8 B = pack4(b_[0], b_[1], b_[2], b_[3]);
      f32x4 cc = {0.f, 0.f, 0.f, 0.f};
      cc = MFMA_B16(A, B, cc, 0, 0, 0);
      if (kg < 2) {
#pragma unroll
        for (int reg = 0; reg < 4; ++reg) {
          const int n = kg * 4 + reg;
          wp[n * 72 + dt * 16 + lo4] = bf16_rne(cc[reg]);
        }
      }
    }
  }
  __syncthreads();   // barrier 2: all wv visible; hs2 arena dead

  // ---------- P4a (MFMA): wave (dtw, ngw); wv+Wf both single-plane -------
  {
    f32x4 cc = {0.f, 0.f, 0.f, 0.f};
#pragma unroll
    for (int nn = 0; nn < 4; ++nn) {
      const int n = ngw * 4 + nn;
      const ushort* ab = ldsu + V2_U + rp8 * 584 + n * 72;
      const short8 a0 = *(const short8*)&ab[kg * 8];
      const short8 a1 = *(const short8*)&ab[32 + kg * 8];
      cc = MFMA_B16(a0, wfB0[nn], cc, 0, 0, 0);
      cc = MFMA_B16(a1, wfB1[nn], cc, 0, 0, 0);
    }
    if (kg < 2) {
#pragma unroll
      for (int reg = 0; reg < 4; ++reg)
        lds[0 + ngw * 512 + (kg * 4 + reg) * 64 + dtw * 16 + lo4] = cc[reg];
    }
  }
  __syncthreads();   // barrier 3

  // ---------- P4b: out = bf + y0 + y1 ----------
  {
    const int d = t & 63;
    out[(size_t)pair0 * 64 + t] = bf[d] + lds[t] + lds[512 + t];
  }
}

extern "C" void kernel_launch(void* const* d_in, const int* in_sizes, int n_in,
                              void* d_out, int out_size, void* d_ws, size_t ws_size,
                              hipStream_t stream) {
  const float* ht  = (const float*)d_in[0];
  const float* hs  = (const float*)d_in[1];
  const int*   len = (const int*)d_in[2];
  const float* Wt  = (const float*)d_in[3];
  const float* bt  = (const float*)d_in[4];
  const float* Ws  = (const float*)d_in[5];
  const float* bs  = (const float*)d_in[6];
  const float* Wf  = (const float*)d_in[7];
  const float* bf  = (const float*)d_in[8];
  float* outp = (float*)d_out;
  float* ws   = (float*)d_ws;

  hipLaunchKernelGGL(prep_kernel, dim3(17), dim3(256), 0, stream,
                     Wt, bt, Ws, bs, Wf, ws);
  hipLaunchKernelGGL(attn_kernel, dim3(4096), dim3(512), 0, stream,
                     ht, hs, len, bf, ws, outp);
}

// Round 18
// 85.042 us; speedup vs baseline: 1.1884x; 1.1884x over previous
//
#include <hip/hip_runtime.h>
#include <hip/hip_bf16.h>

typedef __attribute__((ext_vector_type(8))) short short8;
typedef __attribute__((ext_vector_type(4))) float f32x4;

// dims: S=128, E=256 -> 32768 pairs; H=20, D=64, A=64, NH=8
constexpr float TEMP = 2.5f;    // H / sqrt(A) = 20/8
constexpr float NEGV = -1e9f;

// ---- workspace layout (dwords) ----
constexpr int K_OFF  = 0;       // k[8][64] f32 (TEMP-scaled)
constexpr int P_OFF  = 512;     // p[8][64] f32 (TEMP-scaled; source for PFRAG)
constexpr int Q_OFF  = 1024;    // q[8]     f32 (TEMP-scaled)
constexpr int PFRAG  = 1040;    // P  B-frags [2 ks][2 s][64 lane][4 dw] (1024)
constexpr int MFRAG  = 2064;    // M  B-frags [8 n][2 ks][4 dt][2 s][64][4] (32768)
constexpr int WFRAG  = 34832;   // Wf B-frags SINGLE-plane [8 n][2 ks][4 dt][64][4] (16384)

// ---- main-kernel LDS layout ----
// u16 units:
constexpr int HS2_U   = 0;      // hs bf16 2-plane [2 s][8 p][20 m][72]
constexpr int HS2_PL  = 11520;  //   plane stride; pair 1440; row 72
                                //   (23040 u16; after barrier 2: y f32 @0)
constexpr int V2_U    = 23040;  // V bf16 2-plane [2 s][8 p][n*72+d]
constexpr int V2_PL   = 4672;   //   plane stride; pair 584 (8*72+8 pad)
                                //   (after P2: wv SINGLE-plane overlay in plane-0)
constexpr int HT2_U   = 32384;  // ht bf16 2-way [2 s][8 p][80] (1280 u16)
// f32/u32 units (u16 total 33664 -> f32 offset 16832):
constexpr int ATTP_F = 16832;   // attn packed bf16x2 [8 p][16 mp][9] u32 (1152)
constexpr int C_F    = 17984;   // c[8 p][8 n]               (64)
constexpr int LEN_F  = 18048;   // len[8]                    (8)
constexpr int LDS_FL = 18056;   // 72,224 B -> 2 blocks/CU

#define MFMA_B16 __builtin_amdgcn_mfma_f32_16x16x32_bf16

// ---- bf16 helpers ----
__device__ inline ushort bf16_rne(float x) {
  uint u = __float_as_uint(x);
  u += 0x7FFF + ((u >> 16) & 1);
  return (ushort)(u >> 16);
}
__device__ inline float bf16_f(ushort h) { return __uint_as_float(((uint)h) << 16); }
__device__ inline void split2(float x, ushort& h0, ushort& h1) {
  h0 = bf16_rne(x);
  h1 = bf16_rne(x - bf16_f(h0));
}
__device__ inline ushort split_lvl2(float x, int s) {
  ushort h0 = bf16_rne(x);
  return s == 0 ? h0 : bf16_rne(x - bf16_f(h0));
}
__device__ inline uint pkbf16x2(float a, float b) {
  __hip_bfloat162 h = __float22bfloat162_rn(make_float2(a, b));
  uint u; __builtin_memcpy(&u, &h, 4);
  return u;
}
__device__ inline uint2 pkbf16x4(float4 v) {
  uint2 r; r.x = pkbf16x2(v.x, v.y); r.y = pkbf16x2(v.z, v.w);
  return r;
}
// 4-float 2-plane split: u0 = bf16 pair-packed, u1 = packed residuals
__device__ inline void pksplit4(float4 v, uint2& u0, uint2& u1) {
  u0 = pkbf16x4(v);
  float4 r;
  r.x = v.x - __uint_as_float(u0.x << 16);
  r.y = v.y - __uint_as_float(u0.x & 0xffff0000u);
  r.z = v.z - __uint_as_float(u0.y << 16);
  r.w = v.w - __uint_as_float(u0.y & 0xffff0000u);
  u1 = pkbf16x4(r);
}
__device__ inline short8 pack4(uint a, uint b, uint c, uint d) {
  union { uint u[4]; short8 s; } cv;
  cv.u[0] = a; cv.u[1] = b; cv.u[2] = c; cv.u[3] = d;
  return cv.s;
}

// ============================================================
// prep (grid 17): 0..7 -> M[n] frags + k,p,q ; 8..15 -> Wf frags
//                 (single-plane) ; 16 -> P frags.  (unchanged, verified)
// ============================================================
__global__ __launch_bounds__(256) void prep_kernel(
    const float* __restrict__ Wt, const float* __restrict__ bt,
    const float* __restrict__ Ws, const float* __restrict__ bs,
    const float* __restrict__ Wf, float* __restrict__ ws) {
  __shared__ float AL[64 * 65];
  __shared__ float BL[64 * 65];
  __shared__ float ML[64 * 65];
  const int t = threadIdx.x;
  uint* wsu = (uint*)ws;
  if (blockIdx.x < 8) {
    const int n = blockIdx.x;
#pragma unroll
    for (int i = 0; i < 16; ++i) {
      int idx = i * 256 + t;
      AL[(idx >> 6) * 65 + (idx & 63)] = Wt[n * 4096 + idx];
      BL[(idx >> 6) * 65 + (idx & 63)] = Ws[n * 4096 + idx];
    }
    __syncthreads();
#pragma unroll
    for (int i = 0; i < 16; ++i) {            // M[dp][d] = Wt[dp]·Ws[d] * TEMP
      int idx = i * 256 + t;
      int dp = idx >> 6, d = idx & 63;
      float acc = 0.f;
#pragma unroll 8
      for (int a = 0; a < 64; ++a) acc += AL[dp * 65 + a] * BL[d * 65 + a];
      ML[dp * 65 + d] = acc * TEMP;
    }
    if (t < 64) {
      float acc = 0.f;
#pragma unroll 8
      for (int a = 0; a < 64; ++a) acc += BL[t * 65 + a] * bt[n * 64 + a];
      ws[K_OFF + n * 64 + t] = acc * TEMP;
    } else if (t < 128) {
      int r = t - 64;
      float acc = 0.f;
#pragma unroll 8
      for (int a = 0; a < 64; ++a) acc += AL[r * 65 + a] * bs[n * 64 + a];
      ws[P_OFF + n * 64 + r] = acc * TEMP;
    } else if (t == 128) {
      float acc = 0.f;
      for (int a = 0; a < 64; ++a) acc += bt[n * 64 + a] * bs[n * 64 + a];
      ws[Q_OFF + n] = acc * TEMP;
    }
    __syncthreads();
#pragma unroll
    for (int i = 0; i < 16; ++i) {            // 4096 frag dwords (2-way split)
      int f = i * 256 + t;
      int r = f & 3, lane = (f >> 2) & 63, g = f >> 8;
      int s = g & 1, dt = (g >> 1) & 3, ks = g >> 3;
      int k = ks * 32 + ((lane >> 4) & 3) * 8 + r * 2;
      int d = dt * 16 + (lane & 15);
      uint lo = split_lvl2(ML[k * 65 + d], s);
      uint hi = split_lvl2(ML[(k + 1) * 65 + d], s);
      wsu[MFRAG + n * 4096 + (((ks * 4 + dt) * 2 + s) * 64 + lane) * 4 + r] =
          lo | (hi << 16);
    }
  } else if (blockIdx.x < 16) {
    const int n = blockIdx.x - 8;
#pragma unroll
    for (int i = 0; i < 16; ++i) {            // Wf rows n*64.. (k=dd, col=d)
      int idx = i * 256 + t;
      AL[(idx >> 6) * 65 + (idx & 63)] = Wf[(n * 64 + (idx >> 6)) * 64 + (idx & 63)];
    }
    __syncthreads();
#pragma unroll
    for (int i = 0; i < 8; ++i) {             // 2048 frag dwords (single plane)
      int f = i * 256 + t;
      int r = f & 3, lane = (f >> 2) & 63, g = f >> 8;   // g 0..7
      int dt = g & 3, ks = g >> 2;
      int k = ks * 32 + ((lane >> 4) & 3) * 8 + r * 2;
      int d = dt * 16 + (lane & 15);
      uint lo = bf16_rne(AL[k * 65 + d]);
      uint hi = bf16_rne(AL[(k + 1) * 65 + d]);
      wsu[WFRAG + n * 2048 + ((ks * 4 + dt) * 64 + lane) * 4 + r] =
          lo | (hi << 16);
    }
  } else {
#pragma unroll
    for (int i = 0; i < 2; ++i) {
      int idx = i * 256 + t;                  // 0..511
      int n = idx >> 6, dp = idx & 63;
      float acc = 0.f;
#pragma unroll 8
      for (int a = 0; a < 64; ++a)
        acc += Wt[n * 4096 + dp * 64 + a] * bs[n * 64 + a];
      AL[idx] = acc * TEMP;                   // pL[n][dp]
    }
    __syncthreads();
#pragma unroll
    for (int i = 0; i < 4; ++i) {
      int f = i * 256 + t;
      int r = f & 3, lane = (f >> 2) & 63, g = f >> 8;
      int s = g & 1, ks = g >> 1;
      int k = ks * 32 + ((lane >> 4) & 3) * 8 + r * 2;
      int col = lane & 15;
      uint lo = (col < 8) ? (uint)split_lvl2(AL[col * 64 + k], s) : 0u;
      uint hi = (col < 8) ? (uint)split_lvl2(AL[col * 64 + k + 1], s) : 0u;
      wsu[PFRAG + ((ks * 2 + s) * 64 + lane) * 4 + r] = lo | (hi << 16);
    }
  }
}

// 2-way split-product cluster for global frags (verified R7)
#define SPLIT2_MFMA(FB, DT, CC)                                      \
  {                                                                  \
    short8 b00 = *(const short8*)&(FB)[((0 * 4 + (DT)) * 2 + 0) * 256]; \
    short8 b01 = *(const short8*)&(FB)[((0 * 4 + (DT)) * 2 + 1) * 256]; \
    short8 b10 = *(const short8*)&(FB)[((1 * 4 + (DT)) * 2 + 0) * 256]; \
    short8 b11 = *(const short8*)&(FB)[((1 * 4 + (DT)) * 2 + 1) * 256]; \
    CC = MFMA_B16(a00, b00, CC, 0, 0, 0);                            \
    CC = MFMA_B16(a10, b10, CC, 0, 0, 0);                            \
    CC = MFMA_B16(a00, b01, CC, 0, 0, 0);                            \
    CC = MFMA_B16(a01, b00, CC, 0, 0, 0);                            \
    CC = MFMA_B16(a10, b11, CC, 0, 0, 0);                            \
    CC = MFMA_B16(a11, b10, CC, 0, 0, 0);                            \
  }

// A-frag loads: a00/a10 = plane0 (k-chunk 0/1), a01/a11 = plane1
#define LOAD_A(BASEU, ROWSTR, PLANESTR, ROW, KOFF)                   \
  short8 a00 = *(const short8*)&(BASEU)[(ROW) * (ROWSTR) + (KOFF)];               \
  short8 a01 = *(const short8*)&(BASEU)[(PLANESTR) + (ROW) * (ROWSTR) + (KOFF)];  \
  short8 a10 = *(const short8*)&(BASEU)[(ROW) * (ROWSTR) + 32 + (KOFF)];          \
  short8 a11 = *(const short8*)&(BASEU)[(PLANESTR) + (ROW) * (ROWSTR) + 32 + (KOFF)];

// hs reg-staging index math (quad f = I*512 + t)
#define HV_LOAD(I, DST)                                                      \
  {                                                                          \
    const int f_ = (I) * 512 + t;                                            \
    const int p_ = f_ / 320;                                                 \
    const int s_ = f_ - p_ * 320;                                            \
    DST = *(const float4*)(hs_g + (size_t)(pair0 + p_) * 1280 +              \
                           (s_ >> 4) * 64 + (s_ & 15) * 4);                  \
  }
#define HV_STORE(I, SRC)                                                     \
  {                                                                          \
    const int f_ = (I) * 512 + t;                                            \
    const int p_ = f_ / 320;                                                 \
    const int s_ = f_ - p_ * 320;                                            \
    uint2 u0_, u1_; pksplit4(SRC, u0_, u1_);                                 \
    ushort* d_ = ldsu + HS2_U + p_ * 1440 + (s_ >> 4) * 72 + (s_ & 15) * 4;  \
    *(uint2*)d_ = u0_;                                                       \
    *(uint2*)(d_ + HS2_PL) = u1_;                                            \
  }

// ============================================================
// main: 8 pairs/block, 512 threads (8 waves), grid 4096, 2 blocks/CU.
// R15 structure; hs loads issued AFTER the V MFMA cluster but BEFORE the
// V split/store section (covers latency without crossing the MFMA cluster).
// ============================================================
__global__ __launch_bounds__(512, 4) void attn_kernel(
    const float* __restrict__ ht_g, const float* __restrict__ hs_g,
    const int* __restrict__ len_g, const float* __restrict__ bf,
    const float* __restrict__ wsp, float* __restrict__ out) {
  __shared__ __align__(16) float lds[LDS_FL];
  ushort* ldsu = (ushort*)lds;
  const int t    = threadIdx.x;
  const int lane = t & 63;
  const int w    = t >> 6;
  const int pair0 = blockIdx.x * 8;
  const uint* wsu = (const uint*)wsp;
  const int lo4 = lane & 15, kg = lane >> 4;
  const int rp8 = lo4 & 7;
  const int dtw = w & 3, ngw = w >> 2;

  // ---------- prefetch Wf frags (single-plane) for P4a ----------
  short8 wfB0[4], wfB1[4];
#pragma unroll
  for (int nn = 0; nn < 4; ++nn) {
    const uint* fb = wsu + WFRAG + (ngw * 4 + nn) * 2048 + lane * 4;
    wfB0[nn] = *(const short8*)&fb[(0 * 4 + dtw) * 256];
    wfB1[nn] = *(const short8*)&fb[(1 * 4 + dtw) * 256];
  }

  // ---------- stage ht (2-way bf16 split) + len ----------
  {
    float x = ht_g[(size_t)pair0 * 64 + t];
    ushort h0, h1; split2(x, h0, h1);
    const int p = t >> 6, dp = t & 63;
    ldsu[HT2_U + 0 * 640 + p * 80 + dp] = h0;
    ldsu[HT2_U + 1 * 640 + p * 80 + dp] = h1;
  }
  if (t < 8) lds[LEN_F + t] = (float)len_g[pair0 + t];
  __syncthreads();   // barrier A: ht2 visible

  float4 hv0, hv1, hv2, hv3, hv4;   // hs staging regs (loaded mid-V-phase)

  // ---------- V phase (MFMA): wave = head n; V -> 2-plane bf16 -----------
  {
    const int n = w;
    LOAD_A(ldsu + HT2_U, 80, 640, rp8, kg * 8)
    const uint* fb = wsu + MFRAG + n * 4096 + lane * 4;
    const float* kb = &wsp[K_OFF + n * 64 + lo4];
    float kv0 = kb[0], kv1 = kb[16], kv2 = kb[32], kv3 = kb[48];
    f32x4 c0 = {kv0, kv0, kv0, kv0};
    f32x4 c1 = {kv1, kv1, kv1, kv1};
    f32x4 c2 = {kv2, kv2, kv2, kv2};
    f32x4 c3 = {kv3, kv3, kv3, kv3};
    __builtin_amdgcn_s_setprio(1);
    SPLIT2_MFMA(fb, 0, c0)
    SPLIT2_MFMA(fb, 1, c1)
    SPLIT2_MFMA(fb, 2, c2)
    SPLIT2_MFMA(fb, 3, c3)
    __builtin_amdgcn_s_setprio(0);

    // ---- issue hs loads HERE: covered by the V split/store below, ----
    // ---- without crossing the MFMA cluster (spill-safe placement)  ----
    HV_LOAD(0, hv0) HV_LOAD(1, hv1) HV_LOAD(2, hv2) HV_LOAD(3, hv3) HV_LOAD(4, hv4)

    if (kg < 2) {
#pragma unroll
      for (int reg = 0; reg < 4; ++reg) {
        const int p = kg * 4 + reg;
        ushort* vp = ldsu + V2_U + p * 584 + n * 72 + lo4;
        ushort h0, h1;
        split2(c0[reg], h0, h1); vp[0]  = h0; vp[V2_PL]      = h1;
        split2(c1[reg], h0, h1); vp[16] = h0; vp[V2_PL + 16] = h1;
        split2(c2[reg], h0, h1); vp[32] = h0; vp[V2_PL + 32] = h1;
        split2(c3[reg], h0, h1); vp[48] = h0; vp[V2_PL + 48] = h1;
      }
    }
  }

  // ---------- c (MFMA, wave 0): c[p][n] = q[n] + ht_p·p_n ----------
  if (w == 0) {
    LOAD_A(ldsu + HT2_U, 80, 640, rp8, kg * 8)
    const uint* fbp = wsu + PFRAG + lane * 4;
    short8 b00 = *(const short8*)&fbp[0 * 256];
    short8 b01 = *(const short8*)&fbp[1 * 256];
    short8 b10 = *(const short8*)&fbp[2 * 256];
    short8 b11 = *(const short8*)&fbp[3 * 256];
    float qv = (lo4 < 8) ? wsp[Q_OFF + lo4] : 0.f;
    f32x4 cc = {qv, qv, qv, qv};
    cc = MFMA_B16(a00, b00, cc, 0, 0, 0);
    cc = MFMA_B16(a10, b10, cc, 0, 0, 0);
    cc = MFMA_B16(a00, b01, cc, 0, 0, 0);
    cc = MFMA_B16(a01, b00, cc, 0, 0, 0);
    cc = MFMA_B16(a10, b11, cc, 0, 0, 0);
    cc = MFMA_B16(a11, b10, cc, 0, 0, 0);
    if (kg < 2 && lo4 < 8) {
#pragma unroll
      for (int reg = 0; reg < 4; ++reg)
        lds[C_F + (kg * 4 + reg) * 8 + lo4] = cc[reg];
    }
  }

  // ---------- convert staged hs -> 2-plane bf16 LDS ----------
  HV_STORE(0, hv0) HV_STORE(1, hv1) HV_STORE(2, hv2) HV_STORE(3, hv3) HV_STORE(4, hv4)
  __syncthreads();   // barrier 1: V2, c, hs2 visible

  // ---------- P2 (MFMA): scores + softmax. wave = pair ----------
  {
    const int p = w;
    const int n8 = rp8;
    const int lenp = (int)lds[LEN_F + p];
    const ushort* vb = ldsu + V2_U + p * 584 + n8 * 72;
    const short8 B00 = *(const short8*)&vb[kg * 8];                // ks0 s0
    const short8 B01 = *(const short8*)&vb[V2_PL + kg * 8];        // ks0 s1
    const short8 B10 = *(const short8*)&vb[32 + kg * 8];           // ks1 s0
    const short8 B11 = *(const short8*)&vb[V2_PL + 32 + kg * 8];   // ks1 s1
    const float cv = lds[C_F + p * 8 + n8];
    f32x4 acc0 = {cv, cv, cv, cv};
    f32x4 acc1 = {cv, cv, cv, cv};
    __builtin_amdgcn_s_setprio(1);
    {
      const ushort* ab = ldsu + HS2_U + p * 1440;
      LOAD_A(ab, 72, HS2_PL, lo4, kg * 8)                          // rows 0..15
      acc0 = MFMA_B16(a00, B00, acc0, 0, 0, 0);
      acc0 = MFMA_B16(a10, B10, acc0, 0, 0, 0);
      acc0 = MFMA_B16(a00, B01, acc0, 0, 0, 0);
      acc0 = MFMA_B16(a01, B00, acc0, 0, 0, 0);
      acc0 = MFMA_B16(a10, B11, acc0, 0, 0, 0);
      acc0 = MFMA_B16(a11, B10, acc0, 0, 0, 0);
    }
    {
      const int row = (16 + lo4 < 20) ? (16 + lo4) : 19;           // clamp pad
      const ushort* ab = ldsu + HS2_U + p * 1440;
      LOAD_A(ab, 72, HS2_PL, row, kg * 8)
      acc1 = MFMA_B16(a00, B00, acc1, 0, 0, 0);
      acc1 = MFMA_B16(a10, B10, acc1, 0, 0, 0);
      acc1 = MFMA_B16(a00, B01, acc1, 0, 0, 0);
      acc1 = MFMA_B16(a01, B00, acc1, 0, 0, 0);
      acc1 = MFMA_B16(a10, B11, acc1, 0, 0, 0);
      acc1 = MFMA_B16(a11, B10, acc1, 0, 0, 0);
    }
    __builtin_amdgcn_s_setprio(0);
    // softmax over m (verified pattern)
    float e0[4], e1[4];
    float mx = NEGV;
#pragma unroll
    for (int r = 0; r < 4; ++r) {
      const int m0 = kg * 4 + r;
      const int m1 = 16 + kg * 4 + r;
      e0[r] = (m0 < lenp) ? acc0[r] : NEGV;
      e1[r] = (m1 < lenp) ? acc1[r] : NEGV;
      mx = fmaxf(mx, fmaxf(e0[r], e1[r]));
    }
    mx = fmaxf(mx, __shfl_xor(mx, 16));
    mx = fmaxf(mx, __shfl_xor(mx, 32));
    float sm = 0.f;
#pragma unroll
    for (int r = 0; r < 4; ++r) {
      e0[r] = __expf(e0[r] - mx);
      e1[r] = (kg == 0) ? __expf(e1[r] - mx) : 0.f;    // pad rows m>=20 -> 0
      sm += e0[r] + e1[r];
    }
    sm += __shfl_xor(sm, 16);
    sm += __shfl_xor(sm, 32);
    const float inv = 1.0f / sm;
    // ---- pack attn as bf16 pairs: attp[p][mp][n], mp = m/2, stride 9 ----
    uint* attp = (uint*)&lds[ATTP_F] + p * 144;
    if (lo4 < 8) {
      attp[(kg * 2 + 0) * 9 + lo4] = pkbf16x2(e0[0] * inv, e0[1] * inv);
      attp[(kg * 2 + 1) * 9 + lo4] = pkbf16x2(e0[2] * inv, e0[3] * inv);
      if (kg == 0) {
        attp[8 * 9 + lo4] = pkbf16x2(e1[0] * inv, e1[1] * inv);
        attp[9 * 9 + lo4] = pkbf16x2(e1[2] * inv, e1[3] * inv);
      } else if (kg == 1) {
        attp[14 * 9 + lo4] = 0u; attp[15 * 9 + lo4] = 0u;
      } else if (kg == 2) {
        attp[10 * 9 + lo4] = 0u; attp[11 * 9 + lo4] = 0u;
      } else {
        attp[12 * 9 + lo4] = 0u; attp[13 * 9 + lo4] = 0u;
      }
    }
  }
  // no barrier: P3 pair-local (same wave wrote this pair's attn)

  // ---------- P3 (MFMA): wv[n][d] = sum_m attn[m][n]*hs0[m][d] -----------
  // A: pre-packed bf16 attn pairs, row=n, k=m. B: hs plane-0 scattered.
  // wv output SINGLE-plane bf16 (verified R15).
  {
    const int p = w;
    const uint* attp = (const uint*)&lds[ATTP_F] + p * 144;
    const ushort* hsb = ldsu + HS2_U + p * 1440;
    uint a_[4];
#pragma unroll
    for (int r = 0; r < 4; ++r)
      a_[r] = attp[(kg * 4 + r) * 9 + rp8];    // broadcast across lo4>=8
    const short8 A = pack4(a_[0], a_[1], a_[2], a_[3]);
    ushort* wp = ldsu + V2_U + p * 584;        // overlay V2 plane-0 (dead)
#pragma unroll
    for (int dt = 0; dt < 4; ++dt) {
      uint b_[4];
#pragma unroll
      for (int r = 0; r < 4; ++r) {
        const int m0 = kg * 8 + 2 * r;
        const int d = dt * 16 + lo4;
        uint blo = (m0 < 20) ? (uint)hsb[m0 * 72 + d] : 0u;
        uint bhi = (m0 + 1 < 20) ? (uint)hsb[(m0 + 1) * 72 + d] : 0u;
        b_[r] = blo | (bhi << 16);
      }
      const short8 B = pack4(b_[0], b_[1], b_[2], b_[3]);
      f32x4 cc = {0.f, 0.f, 0.f, 0.f};
      cc = MFMA_B16(A, B, cc, 0, 0, 0);
      if (kg < 2) {
#pragma unroll
        for (int reg = 0; reg < 4; ++reg) {
          const int n = kg * 4 + reg;
          wp[n * 72 + dt * 16 + lo4] = bf16_rne(cc[reg]);
        }
      }
    }
  }
  __syncthreads();   // barrier 2: all wv visible; hs2 arena dead

  // ---------- P4a (MFMA): wave (dtw, ngw); wv+Wf both single-plane -------
  {
    f32x4 cc = {0.f, 0.f, 0.f, 0.f};
#pragma unroll
    for (int nn = 0; nn < 4; ++nn) {
      const int n = ngw * 4 + nn;
      const ushort* ab = ldsu + V2_U + rp8 * 584 + n * 72;
      const short8 a0 = *(const short8*)&ab[kg * 8];
      const short8 a1 = *(const short8*)&ab[32 + kg * 8];
      cc = MFMA_B16(a0, wfB0[nn], cc, 0, 0, 0);
      cc = MFMA_B16(a1, wfB1[nn], cc, 0, 0, 0);
    }
    if (kg < 2) {
#pragma unroll
      for (int reg = 0; reg < 4; ++reg)
        lds[0 + ngw * 512 + (kg * 4 + reg) * 64 + dtw * 16 + lo4] = cc[reg];
    }
  }
  __syncthreads();   // barrier 3

  // ---------- P4b: out = bf + y0 + y1 ----------
  {
    const int d = t & 63;
    out[(size_t)pair0 * 64 + t] = bf[d] + lds[t] + lds[512 + t];
  }
}

extern "C" void kernel_launch(void* const* d_in, const int* in_sizes, int n_in,
                              void* d_out, int out_size, void* d_ws, size_t ws_size,
                              hipStream_t stream) {
  const float* ht  = (const float*)d_in[0];
  const float* hs  = (const float*)d_in[1];
  const int*   len = (const int*)d_in[2];
  const float* Wt  = (const float*)d_in[3];
  const float* bt  = (const float*)d_in[4];
  const float* Ws  = (const float*)d_in[5];
  const float* bs  = (const float*)d_in[6];
  const float* Wf  = (const float*)d_in[7];
  const float* bf  = (const float*)d_in[8];
  float* outp = (float*)d_out;
  float* ws   = (float*)d_ws;

  hipLaunchKernelGGL(prep_kernel, dim3(17), dim3(256), 0, stream,
                     Wt, bt, Ws, bs, Wf, ws);
  hipLaunchKernelGGL(attn_kernel, dim3(4096), dim3(512), 0, stream,
                     ht, hs, len, bf, ws, outp);
}